// Round 15
// baseline (176.154 us; speedup 1.0000x reference)
//
#include <hip/hip_runtime.h>
#include <hip/hip_bf16.h>

#define HW   3136   // 56*56
#define WID  56
#define CIN  256
#define NH   8
#define HD   32
#define KK   49
#define NW   8

// ws layout (byte offsets):
//   kmap  f32  [2*NH*HW*HD] @ 0
//   qmap  bf16              @ 6,422,528
//   vmap  bf16              @ 9,633,792   (end 12,845,056)
#define QOFFB 6422528
#define VOFFB 9633792

#define SROWS 196   // 14*14 staged halo window
#define VSTR  40    // ushorts per staged q row (80 B stride, bank-balanced b128)
#define LSTR  52    // floats per Llds row: 208 B = 16B-aligned, bank-spread

typedef short  bf16x8 __attribute__((ext_vector_type(8)));
typedef float  f32x4  __attribute__((ext_vector_type(4)));
typedef float  f32x2  __attribute__((ext_vector_type(2)));

__device__ __forceinline__ unsigned f2bf(float x) {        // RNE f32->bf16 bits
    unsigned u = __float_as_uint(x);
    return (u + 0x7fffu + ((u >> 16) & 1u)) >> 16;
}
__device__ __forceinline__ float bfb2f(unsigned h)  { return __uint_as_float(h << 16); }
__device__ __forceinline__ float bf2f_lo(unsigned u){ return __uint_as_float(u << 16); }
__device__ __forceinline__ float bf2f_hi(unsigned u){ return __uint_as_float(u & 0xffff0000u); }

// ---------------------------------------------------------------------------
// proj_kernel v5 (r14 verbatim): 64px x 64m tiles, grid 98x12, LDS 32KB.
// k blocks: 3-term split (f32-exact); q/v blocks: hi-only.
// ---------------------------------------------------------------------------
__global__ __launch_bounds__(512, 4) void proj_kernel(
    const float* __restrict__ x,
    const float* __restrict__ Wk,
    const float* __restrict__ Wq,
    const float* __restrict__ Wv,
    float* __restrict__ kmap,
    unsigned short* __restrict__ qmap,
    unsigned short* __restrict__ vmap)
{
    __shared__ unsigned short Xh[64 * 64];    // 8 KB
    __shared__ unsigned short Xl[64 * 64];    // 8 KB (k blocks only)
    __shared__ unsigned short Wh[64 * 64];    // 8 KB
    __shared__ unsigned short Wl[64 * 64];    // 8 KB (k blocks only)

    const int pr0 = blockIdx.x * 64;         // global pixel-row base
    const int m0  = blockIdx.y * 64;
    const int proj  = m0 >> 8;               // block-uniform
    const int msub0 = m0 & 255;
    const bool split = (proj == 0);          // exact path for k only

    const int t    = threadIdx.x;
    const int lane = t & 63;
    const int w    = t >> 6;
    const int wm   = (w >> 2) << 5;          // 0,32
    const int wp   = (w & 3) << 4;           // 0,16,32,48
    const int l15  = lane & 15;
    const int kg   = lane >> 4;
    const unsigned sz = (unsigned)(l15 & 7) << 4;

    f32x4 acc0 = {0.f, 0.f, 0.f, 0.f};
    f32x4 acc1 = acc0;

    // ---- X staging: row pxl = t&63, c-octet cph = t>>6 ----
    const int pxl = t & 63;
    const int cph = t >> 6;                  // 0..7
    const int prow_s = pr0 + pxl;
    const int bbs = (prow_s >= HW) ? 1 : 0;
    const int ps  = prow_s - bbs * HW;
    const float* xb = x + (size_t)(bbs * CIN + cph * 8) * HW + ps;
    const unsigned xoff = (unsigned)(pxl * 128 + ((cph * 16) ^ ((pxl & 7) << 4)));

    // ---- W staging: mrow = t>>3, c8 = t&7 ----
    const int mrow = t >> 3;                 // 0..63
    const int c8   = t & 7;
    const float* Wp = (proj == 0) ? Wk : (proj == 1 ? Wq : Wv);
    const float* wb = Wp + (size_t)(msub0 + mrow) * CIN + c8 * 8;
    const unsigned woffb = (unsigned)(mrow * 128 + ((c8 * 16) ^ ((mrow & 7) << 4)));

    float xv[8];
    float wv[8];
    #pragma unroll
    for (int i = 0; i < 8; ++i) xv[i] = xb[(size_t)i * HW];
    *(float4*)&wv[0] = *(const float4*)wb;
    *(float4*)&wv[4] = *(const float4*)(wb + 4);

    for (int c0 = 0; c0 < CIN; c0 += 64) {
        if (c0) __syncthreads();

        {
            unsigned h[8];
            #pragma unroll
            for (int e = 0; e < 8; ++e) h[e] = f2bf(xv[e]);
            uint4 uh = make_uint4(h[0]|(h[1]<<16), h[2]|(h[3]<<16),
                                  h[4]|(h[5]<<16), h[6]|(h[7]<<16));
            *(uint4*)((char*)Xh + xoff) = uh;

            unsigned wh[8];
            #pragma unroll
            for (int e = 0; e < 8; ++e) wh[e] = f2bf(wv[e]);
            uint4 uwh = make_uint4(wh[0]|(wh[1]<<16), wh[2]|(wh[3]<<16),
                                   wh[4]|(wh[5]<<16), wh[6]|(wh[7]<<16));
            *(uint4*)((char*)Wh + woffb) = uwh;

            if (split) {
                unsigned lo[8];
                #pragma unroll
                for (int e = 0; e < 8; ++e) lo[e] = f2bf(xv[e] - bfb2f(h[e]));
                uint4 ul = make_uint4(lo[0]|(lo[1]<<16), lo[2]|(lo[3]<<16),
                                      lo[4]|(lo[5]<<16), lo[6]|(lo[7]<<16));
                *(uint4*)((char*)Xl + xoff) = ul;

                unsigned wlo[8];
                #pragma unroll
                for (int e = 0; e < 8; ++e) wlo[e] = f2bf(wv[e] - bfb2f(wh[e]));
                uint4 uwl = make_uint4(wlo[0]|(wlo[1]<<16), wlo[2]|(wlo[3]<<16),
                                       wlo[4]|(wlo[5]<<16), wlo[6]|(wlo[7]<<16));
                *(uint4*)((char*)Wl + woffb) = uwl;
            }
        }

        if (c0 + 64 < CIN) {
            #pragma unroll
            for (int i = 0; i < 8; ++i) xv[i] = xb[(size_t)(c0 + 64 + i) * HW];
            *(float4*)&wv[0] = *(const float4*)(wb + c0 + 64);
            *(float4*)&wv[4] = *(const float4*)(wb + c0 + 64 + 4);
        }
        __syncthreads();

        #pragma unroll
        for (int kk = 0; kk < 2; ++kk) {
            const unsigned cb = ((unsigned)(kk * 64 + kg * 16)) ^ sz;
            const char* whb = (const char*)Wh + cb;
            const char* xhb = (const char*)Xh + cb;
            bf16x8 ah0 = *(const bf16x8*)(whb + (wm + l15) * 128);
            bf16x8 ah1 = *(const bf16x8*)(whb + (wm + 16 + l15) * 128);
            bf16x8 bh  = *(const bf16x8*)(xhb + (wp + l15) * 128);
            acc0 = __builtin_amdgcn_mfma_f32_16x16x32_bf16(ah0, bh, acc0, 0, 0, 0);
            acc1 = __builtin_amdgcn_mfma_f32_16x16x32_bf16(ah1, bh, acc1, 0, 0, 0);
            if (split) {
                const char* wlb = (const char*)Wl + cb;
                const char* xlb = (const char*)Xl + cb;
                bf16x8 al0 = *(const bf16x8*)(wlb + (wm + l15) * 128);
                bf16x8 al1 = *(const bf16x8*)(wlb + (wm + 16 + l15) * 128);
                bf16x8 bl  = *(const bf16x8*)(xlb + (wp + l15) * 128);
                acc0 = __builtin_amdgcn_mfma_f32_16x16x32_bf16(ah0, bl, acc0, 0, 0, 0);
                acc1 = __builtin_amdgcn_mfma_f32_16x16x32_bf16(ah1, bl, acc1, 0, 0, 0);
                acc0 = __builtin_amdgcn_mfma_f32_16x16x32_bf16(al0, bh, acc0, 0, 0, 0);
                acc1 = __builtin_amdgcn_mfma_f32_16x16x32_bf16(al1, bh, acc1, 0, 0, 0);
            }
        }
    }

    #define ST(ACC, MI) { \
        int prow = pr0 + wp + l15; \
        int bb = (prow >= HW) ? 1 : 0; \
        int pp = prow - bb * HW; \
        int msub = msub0 + wm + (MI) * 16 + kg * 4; \
        size_t base = ((size_t)(bb * NH + (msub >> 5)) * HW + pp) * HD + (msub & 31); \
        if (proj == 0) { \
            *(float4*)&kmap[base] = make_float4(ACC[0], ACC[1], ACC[2], ACC[3]); \
        } else { \
            uint2 u; \
            u.x = f2bf(ACC[0]) | (f2bf(ACC[1]) << 16); \
            u.y = f2bf(ACC[2]) | (f2bf(ACC[3]) << 16); \
            unsigned short* mp = (proj == 1) ? qmap : vmap; \
            *(uint2*)&mp[base] = u; } }
    ST(acc0, 0) ST(acc1, 1)
    #undef ST
}

// ---------------------------------------------------------------------------
// attn_kernel v15: PV reads v DIRECTLY from global (L1/L2-hot, TA pipe)
// instead of LDS — removes the 49 b64 LDS reads/thread (the largest LDS
// term) and the entire v staging.  OOB: a_eff = valid ? e*fw : 0 with a
// safe clamped address -> product is exactly 0, same accumulation order,
// bit-identical output (canary: absmax 0.04492188).
// ---------------------------------------------------------------------------
__global__ __launch_bounds__(512, 6) void attn_kernel(
    const float* __restrict__ kmap,
    const unsigned short* __restrict__ qmap,
    const unsigned short* __restrict__ vmap,
    const float* __restrict__ rel_h,
    const float* __restrict__ rel_w,
    float* __restrict__ out)
{
    __shared__ unsigned short stq[SROWS * VSTR];   // 15680 B
    __shared__ float          Llds[64 * LSTR];     // 13312 B
    __shared__ float          rhw[14][64];         //  3584 B
    __shared__ float          mpart[NW][64];       //  2048 B
    __shared__ float          spart[NW][64];       //  2048 B  (total 36672 B)

    const int bid = blockIdx.x;
    const int swz = (bid & 7) * 98 + (bid >> 3);   // XCD-bijective (784 = 8*98)
    const int b    = swz / 392;
    const int rem  = swz - b * 392;
    const int n    = rem / 49;
    const int tile = rem - n * 49;
    const int ty0  = (tile / 7) * 8;
    const int tx0  = (tile % 7) * 8;

    const int t    = threadIdx.x;
    const int lane = t & 63;
    const int w    = t >> 6;
    const int py   = lane >> 3;
    const int px   = lane & 7;
    const int yy   = ty0 + py;
    const int xx   = tx0 + px;
    const int pix  = yy * WID + xx;

    const size_t mb   = (size_t)(b * NH + n) * HW;
    const size_t krec = (mb + pix) * HD;

    // ---- center key vector as 16 float2 pairs ----
    f32x2 kc2[16];
    #pragma unroll
    for (int c4 = 0; c4 < 8; ++c4) {
        float4 kv = *(const float4*)&kmap[krec + c4 * 4];
        kc2[c4 * 2 + 0] = (f32x2){kv.x, kv.y};
        kc2[c4 * 2 + 1] = (f32x2){kv.z, kv.w};
    }

    // ---- validity flags for the 7x7 window ----
    bool vy[7], vx[7];
    #pragma unroll
    for (int i = 0; i < 7; ++i) {
        vy[i] = (unsigned)(yy + i - 3) < 56u;
        vx[i] = (unsigned)(xx + i - 3) < 56u;
    }

    // ---- stage q only (bf16 straight copy) ----
    #pragma unroll
    for (int kk = 0; kk < 2; ++kk) {
        int f = t + kk * 512;
        if (f < SROWS * 4) {
            int sp = f >> 2, ch = f & 3;
            int sy = sp / 14, sx = sp - sy * 14;
            int gy = ty0 + sy - 3, gx = tx0 + sx - 3;
            uint4 q = make_uint4(0, 0, 0, 0);
            if ((unsigned)gy < 56u && (unsigned)gx < 56u)
                q = *(const uint4*)&qmap[(mb + gy * WID + gx) * HD + ch * 8];
            *(uint4*)&stq[sp * VSTR + ch * 8] = q;
        }
    }

    // ---- rel bias dots, once per block (waves 0..6), 2-way split ----
    if (w < 7) {
        float a0 = 0.f, a1 = 0.f, c0 = 0.f, c1 = 0.f;
        #pragma unroll
        for (int dd = 0; dd < 8; ++dd) {
            a0 += rel_h[(n * 7 + w) * 16 + dd]     * kc2[dd >> 1][dd & 1];
            a1 += rel_h[(n * 7 + w) * 16 + 8 + dd] * kc2[(8 + dd) >> 1][dd & 1];
            c0 += rel_w[(n * 7 + w) * 16 + dd]     * kc2[(16 + dd) >> 1][dd & 1];
            c1 += rel_w[(n * 7 + w) * 16 + 8 + dd] * kc2[(24 + dd) >> 1][dd & 1];
        }
        rhw[w][lane]     = a0 + a1;
        rhw[7 + w][lane] = c0 + c1;
    }
    __syncthreads();   // barrier 1: staging + rhw visible

    // ---- QK: wave w owns cells k = w + 8c; packed f32x2 dots; local max ----
    const int spc = py * 14 + px;
    float l[7];
    float lm = -1e30f;
    #pragma unroll
    for (int c = 0; c < 7; ++c) {
        const int k = w + c * NW;
        if (k < KK) {                       // wave-uniform
            int i = k / 7, j = k - i * 7;
            const unsigned short* qr = &stq[(spc + i * 14 + j) * VSTR];
            f32x2 s0 = {0.f, 0.f}, s1 = {0.f, 0.f}, s2 = {0.f, 0.f}, s3 = {0.f, 0.f};
            #pragma unroll
            for (int c4 = 0; c4 < 4; ++c4) {
                uint4 qv = *(const uint4*)&qr[c4 * 8];
                f32x2 qa = {bf2f_lo(qv.x), bf2f_hi(qv.x)};
                f32x2 qb = {bf2f_lo(qv.y), bf2f_hi(qv.y)};
                f32x2 qc = {bf2f_lo(qv.z), bf2f_hi(qv.z)};
                f32x2 qd = {bf2f_lo(qv.w), bf2f_hi(qv.w)};
                s0 = s0 + kc2[c4 * 4 + 0] * qa;
                s1 = s1 + kc2[c4 * 4 + 1] * qb;
                s2 = s2 + kc2[c4 * 4 + 2] * qc;
                s3 = s3 + kc2[c4 * 4 + 3] * qd;
            }
            f32x2 st = (s0 + s1) + (s2 + s3);
            float lv = (rhw[i][lane] + rhw[7 + j][lane]) + (st.x + st.y);
            l[c] = lv;
            lm = fmaxf(lm, lv);
        } else {
            l[c] = -1e30f;
        }
    }
    float ls = 0.f;
    float* Lme = &Llds[lane * LSTR];
    #pragma unroll
    for (int c = 0; c < 7; ++c) {
        const int k = w + c * NW;
        if (k < KK) {
            float e = __expf(l[c] - lm);
            ls += e;
            Lme[k] = e;
        }
    }
    mpart[w][lane] = lm;
    spart[w][lane] = ls;
    __syncthreads();   // barrier 2: partials + Llds visible

    // ---- merge partials: m, s, per-wave factors fw[] (inv folded in) ----
    float m = mpart[0][lane];
    #pragma unroll
    for (int ww = 1; ww < NW; ++ww) m = fmaxf(m, mpart[ww][lane]);
    float fw[NW];
    float s = 0.f;
    #pragma unroll
    for (int ww = 0; ww < NW; ++ww) {
        float f = __expf(mpart[ww][lane] - m);
        s += spart[ww][lane] * f;
        fw[ww] = f;
    }
    const float inv = 1.f / s;
    #pragma unroll
    for (int ww = 0; ww < NW; ++ww) fw[ww] *= inv;

    // ---- PV: wave w owns d = 4w..4w+3; e from LDS b128, v from GLOBAL ----
    const int d0 = w * 4;
    const unsigned short* vbase = vmap + krec + d0;   // center record, this d
    const float* Lrow = &Llds[lane * LSTR];
    f32x2 o01 = {0.f, 0.f}, o23 = {0.f, 0.f};
    #pragma unroll
    for (int jc = 0; jc < 12; ++jc) {
        f32x4 e4 = *(const f32x4*)&Lrow[jc * 4];
        #pragma unroll
        for (int q = 0; q < 4; ++q) {
            const int k = jc * 4 + q;              // 0..47, compile-time
            const int i = k / 7, j = k - i * 7;
            const int CST = ((i - 3) * WID + (j - 3)) * HD;   // element offset
            bool valid = vy[i] && vx[j];
            float a = valid ? e4[q] * fw[k & 7] : 0.f;
            uint2 vv = *(const uint2*)(vbase + (valid ? CST : 0));
            f32x2 a2 = {a, a};
            f32x2 v01 = {bf2f_lo(vv.x), bf2f_hi(vv.x)};
            f32x2 v23 = {bf2f_lo(vv.y), bf2f_hi(vv.y)};
            o01 = o01 + a2 * v01;
            o23 = o23 + a2 * v23;
        }
    }
    {   // tail cell k = 48 (i=6, j=6)
        const int CST = (3 * WID + 3) * HD;
        bool valid = vy[6] && vx[6];
        float a = valid ? Lrow[48] * fw[48 & 7] : 0.f;
        uint2 vv = *(const uint2*)(vbase + (valid ? CST : 0));
        f32x2 a2 = {a, a};
        f32x2 v01 = {bf2f_lo(vv.x), bf2f_hi(vv.x)};
        f32x2 v23 = {bf2f_lo(vv.y), bf2f_hi(vv.y)};
        o01 = o01 + a2 * v01;
        o23 = o23 + a2 * v23;
    }
    const size_t ob = ((size_t)(b * NH + n) * HD + d0) * HW + pix;
    out[ob]          = o01.x;
    out[ob + HW]     = o01.y;
    out[ob + 2 * HW] = o23.x;
    out[ob + 3 * HW] = o23.y;
}

extern "C" void kernel_launch(void* const* d_in, const int* in_sizes, int n_in,
                              void* d_out, int out_size, void* d_ws, size_t ws_size,
                              hipStream_t stream) {
    const float* x     = (const float*)d_in[0];
    const float* Wk    = (const float*)d_in[1];
    const float* Wq    = (const float*)d_in[2];
    const float* Wv    = (const float*)d_in[3];
    const float* rel_h = (const float*)d_in[4];
    const float* rel_w = (const float*)d_in[5];

    char* wsb = (char*)d_ws;
    float*          kmap = (float*)wsb;
    unsigned short* qmap = (unsigned short*)(wsb + QOFFB);
    unsigned short* vmap = (unsigned short*)(wsb + VOFFB);
    float* out = (float*)d_out;

    hipLaunchKernelGGL(proj_kernel, dim3(98, 12), dim3(512), 0, stream,
                       x, Wk, Wq, Wv, kmap, qmap, vmap);
    hipLaunchKernelGGL(attn_kernel, dim3(784),    dim3(512), 0, stream,
                       kmap, qmap, vmap, rel_h, rel_w, out);
}

// Round 16
// 41.967 us; speedup vs baseline: 4.1975x; 4.1975x over previous
//
#include <hip/hip_runtime.h>
#include <hip/hip_bf16.h>

#define HW   3136   // 56*56
#define WID  56
#define CIN  256
#define NH   8
#define HD   32
#define KK   49
#define NW   8

// ws layout (byte offsets):
//   kmap  f32  [2*NH*HW*HD] @ 0
//   qmap  bf16              @ 6,422,528
//   vmap  bf16              @ 9,633,792   (end 12,845,056)
#define QOFFB 6422528
#define VOFFB 9633792

#define SROWS 196   // 14*14 staged halo window
#define VSTR  40    // ushorts per staged row (80 B stride, bank-balanced for b128)
#define LSTR  52    // floats per Llds row: 208 B = 16B-aligned, bank-spread

typedef short  bf16x8 __attribute__((ext_vector_type(8)));
typedef float  f32x4  __attribute__((ext_vector_type(4)));
typedef float  f32x2  __attribute__((ext_vector_type(2)));

__device__ __forceinline__ unsigned f2bf(float x) {        // RNE f32->bf16 bits
    unsigned u = __float_as_uint(x);
    return (u + 0x7fffu + ((u >> 16) & 1u)) >> 16;
}
__device__ __forceinline__ float bfb2f(unsigned h)  { return __uint_as_float(h << 16); }
__device__ __forceinline__ float bf2f_lo(unsigned u){ return __uint_as_float(u << 16); }
__device__ __forceinline__ float bf2f_hi(unsigned u){ return __uint_as_float(u & 0xffff0000u); }

// ---------------------------------------------------------------------------
// proj_kernel v5 (r14 verbatim): 64px x 64m tiles, grid 98x12, LDS 32KB.
// k blocks: 3-term split (f32-exact); q/v blocks: hi-only.
// ---------------------------------------------------------------------------
__global__ __launch_bounds__(512, 4) void proj_kernel(
    const float* __restrict__ x,
    const float* __restrict__ Wk,
    const float* __restrict__ Wq,
    const float* __restrict__ Wv,
    float* __restrict__ kmap,
    unsigned short* __restrict__ qmap,
    unsigned short* __restrict__ vmap)
{
    __shared__ unsigned short Xh[64 * 64];    // 8 KB
    __shared__ unsigned short Xl[64 * 64];    // 8 KB (k blocks only)
    __shared__ unsigned short Wh[64 * 64];    // 8 KB
    __shared__ unsigned short Wl[64 * 64];    // 8 KB (k blocks only)

    const int pr0 = blockIdx.x * 64;         // global pixel-row base
    const int m0  = blockIdx.y * 64;
    const int proj  = m0 >> 8;               // block-uniform
    const int msub0 = m0 & 255;
    const bool split = (proj == 0);          // exact path for k only

    const int t    = threadIdx.x;
    const int lane = t & 63;
    const int w    = t >> 6;
    const int wm   = (w >> 2) << 5;          // 0,32
    const int wp   = (w & 3) << 4;           // 0,16,32,48
    const int l15  = lane & 15;
    const int kg   = lane >> 4;
    const unsigned sz = (unsigned)(l15 & 7) << 4;

    f32x4 acc0 = {0.f, 0.f, 0.f, 0.f};
    f32x4 acc1 = acc0;

    // ---- X staging: row pxl = t&63, c-octet cph = t>>6 ----
    const int pxl = t & 63;
    const int cph = t >> 6;                  // 0..7
    const int prow_s = pr0 + pxl;
    const int bbs = (prow_s >= HW) ? 1 : 0;
    const int ps  = prow_s - bbs * HW;
    const float* xb = x + (size_t)(bbs * CIN + cph * 8) * HW + ps;
    const unsigned xoff = (unsigned)(pxl * 128 + ((cph * 16) ^ ((pxl & 7) << 4)));

    // ---- W staging: mrow = t>>3, c8 = t&7 ----
    const int mrow = t >> 3;                 // 0..63
    const int c8   = t & 7;
    const float* Wp = (proj == 0) ? Wk : (proj == 1 ? Wq : Wv);
    const float* wb = Wp + (size_t)(msub0 + mrow) * CIN + c8 * 8;
    const unsigned woffb = (unsigned)(mrow * 128 + ((c8 * 16) ^ ((mrow & 7) << 4)));

    float xv[8];
    float wv[8];
    #pragma unroll
    for (int i = 0; i < 8; ++i) xv[i] = xb[(size_t)i * HW];
    *(float4*)&wv[0] = *(const float4*)wb;
    *(float4*)&wv[4] = *(const float4*)(wb + 4);

    for (int c0 = 0; c0 < CIN; c0 += 64) {
        if (c0) __syncthreads();

        {
            unsigned h[8];
            #pragma unroll
            for (int e = 0; e < 8; ++e) h[e] = f2bf(xv[e]);
            uint4 uh = make_uint4(h[0]|(h[1]<<16), h[2]|(h[3]<<16),
                                  h[4]|(h[5]<<16), h[6]|(h[7]<<16));
            *(uint4*)((char*)Xh + xoff) = uh;

            unsigned wh[8];
            #pragma unroll
            for (int e = 0; e < 8; ++e) wh[e] = f2bf(wv[e]);
            uint4 uwh = make_uint4(wh[0]|(wh[1]<<16), wh[2]|(wh[3]<<16),
                                   wh[4]|(wh[5]<<16), wh[6]|(wh[7]<<16));
            *(uint4*)((char*)Wh + woffb) = uwh;

            if (split) {
                unsigned lo[8];
                #pragma unroll
                for (int e = 0; e < 8; ++e) lo[e] = f2bf(xv[e] - bfb2f(h[e]));
                uint4 ul = make_uint4(lo[0]|(lo[1]<<16), lo[2]|(lo[3]<<16),
                                      lo[4]|(lo[5]<<16), lo[6]|(lo[7]<<16));
                *(uint4*)((char*)Xl + xoff) = ul;

                unsigned wlo[8];
                #pragma unroll
                for (int e = 0; e < 8; ++e) wlo[e] = f2bf(wv[e] - bfb2f(wh[e]));
                uint4 uwl = make_uint4(wlo[0]|(wlo[1]<<16), wlo[2]|(wlo[3]<<16),
                                       wlo[4]|(wlo[5]<<16), wlo[6]|(wlo[7]<<16));
                *(uint4*)((char*)Wl + woffb) = uwl;
            }
        }

        if (c0 + 64 < CIN) {
            #pragma unroll
            for (int i = 0; i < 8; ++i) xv[i] = xb[(size_t)(c0 + 64 + i) * HW];
            *(float4*)&wv[0] = *(const float4*)(wb + c0 + 64);
            *(float4*)&wv[4] = *(const float4*)(wb + c0 + 64 + 4);
        }
        __syncthreads();

        #pragma unroll
        for (int kk = 0; kk < 2; ++kk) {
            const unsigned cb = ((unsigned)(kk * 64 + kg * 16)) ^ sz;
            const char* whb = (const char*)Wh + cb;
            const char* xhb = (const char*)Xh + cb;
            bf16x8 ah0 = *(const bf16x8*)(whb + (wm + l15) * 128);
            bf16x8 ah1 = *(const bf16x8*)(whb + (wm + 16 + l15) * 128);
            bf16x8 bh  = *(const bf16x8*)(xhb + (wp + l15) * 128);
            acc0 = __builtin_amdgcn_mfma_f32_16x16x32_bf16(ah0, bh, acc0, 0, 0, 0);
            acc1 = __builtin_amdgcn_mfma_f32_16x16x32_bf16(ah1, bh, acc1, 0, 0, 0);
            if (split) {
                const char* wlb = (const char*)Wl + cb;
                const char* xlb = (const char*)Xl + cb;
                bf16x8 al0 = *(const bf16x8*)(wlb + (wm + l15) * 128);
                bf16x8 al1 = *(const bf16x8*)(wlb + (wm + 16 + l15) * 128);
                bf16x8 bl  = *(const bf16x8*)(xlb + (wp + l15) * 128);
                acc0 = __builtin_amdgcn_mfma_f32_16x16x32_bf16(ah0, bl, acc0, 0, 0, 0);
                acc1 = __builtin_amdgcn_mfma_f32_16x16x32_bf16(ah1, bl, acc1, 0, 0, 0);
                acc0 = __builtin_amdgcn_mfma_f32_16x16x32_bf16(al0, bh, acc0, 0, 0, 0);
                acc1 = __builtin_amdgcn_mfma_f32_16x16x32_bf16(al1, bh, acc1, 0, 0, 0);
            }
        }
    }

    #define ST(ACC, MI) { \
        int prow = pr0 + wp + l15; \
        int bb = (prow >= HW) ? 1 : 0; \
        int pp = prow - bb * HW; \
        int msub = msub0 + wm + (MI) * 16 + kg * 4; \
        size_t base = ((size_t)(bb * NH + (msub >> 5)) * HW + pp) * HD + (msub & 31); \
        if (proj == 0) { \
            *(float4*)&kmap[base] = make_float4(ACC[0], ACC[1], ACC[2], ACC[3]); \
        } else { \
            uint2 u; \
            u.x = f2bf(ACC[0]) | (f2bf(ACC[1]) << 16); \
            u.y = f2bf(ACC[2]) | (f2bf(ACC[3]) << 16); \
            unsigned short* mp = (proj == 1) ? qmap : vmap; \
            *(uint2*)&mp[base] = u; } }
    ST(acc0, 0) ST(acc1, 1)
    #undef ST
}

// ---------------------------------------------------------------------------
// attn_kernel — r13/r14 verbatim (f32 transposed Llds, v staged in LDS,
// f32x2 packed math).  v MUST stay in LDS: r15 showed global-v scatters
// 64 cache lines per wave-load (FETCH 135 MB, 174 µs).
// ---------------------------------------------------------------------------
__global__ __launch_bounds__(512, 6) void attn_kernel(
    const float* __restrict__ kmap,
    const unsigned short* __restrict__ qmap,
    const unsigned short* __restrict__ vmap,
    const float* __restrict__ rel_h,
    const float* __restrict__ rel_w,
    float* __restrict__ out)
{
    __shared__ unsigned short stq[SROWS * VSTR];   // 15680 B
    __shared__ unsigned short stv[SROWS * VSTR];   // 15680 B
    __shared__ float          Llds[64 * LSTR];     // 13312 B
    __shared__ float          rhw[14][64];         //  3584 B
    __shared__ float          mpart[NW][64];       //  2048 B
    __shared__ float          spart[NW][64];       //  2048 B  (total 52352 B)

    const int bid = blockIdx.x;
    const int swz = (bid & 7) * 98 + (bid >> 3);   // XCD-bijective (784 = 8*98)
    const int b    = swz / 392;
    const int rem  = swz - b * 392;
    const int n    = rem / 49;
    const int tile = rem - n * 49;
    const int ty0  = (tile / 7) * 8;
    const int tx0  = (tile % 7) * 8;

    const int t    = threadIdx.x;
    const int lane = t & 63;
    const int w    = t >> 6;
    const int py   = lane >> 3;
    const int px   = lane & 7;
    const int pix  = (ty0 + py) * WID + tx0 + px;

    const size_t mb   = (size_t)(b * NH + n) * HW;
    const size_t krec = (mb + pix) * HD;

    // ---- center key vector as 16 float2 pairs ----
    f32x2 kc2[16];
    #pragma unroll
    for (int c4 = 0; c4 < 8; ++c4) {
        float4 kv = *(const float4*)&kmap[krec + c4 * 4];
        kc2[c4 * 2 + 0] = (f32x2){kv.x, kv.y};
        kc2[c4 * 2 + 1] = (f32x2){kv.z, kv.w};
    }

    // ---- stage q and v (bf16 straight copy) ----
    #pragma unroll
    for (int kk = 0; kk < 2; ++kk) {
        int f = t + kk * 512;
        if (f < SROWS * 4) {
            int sp = f >> 2, ch = f & 3;
            int sy = sp / 14, sx = sp - sy * 14;
            int gy = ty0 + sy - 3, gx = tx0 + sx - 3;
            uint4 q = make_uint4(0, 0, 0, 0), v = make_uint4(0, 0, 0, 0);
            if ((unsigned)gy < 56u && (unsigned)gx < 56u) {
                size_t rec = (mb + gy * WID + gx) * HD + ch * 8;
                q = *(const uint4*)&qmap[rec];
                v = *(const uint4*)&vmap[rec];
            }
            *(uint4*)&stq[sp * VSTR + ch * 8] = q;
            *(uint4*)&stv[sp * VSTR + ch * 8] = v;
        }
    }

    // ---- rel bias dots, once per block (waves 0..6), 2-way split ----
    if (w < 7) {
        float a0 = 0.f, a1 = 0.f, c0 = 0.f, c1 = 0.f;
        #pragma unroll
        for (int dd = 0; dd < 8; ++dd) {
            a0 += rel_h[(n * 7 + w) * 16 + dd]     * kc2[dd >> 1][dd & 1];
            a1 += rel_h[(n * 7 + w) * 16 + 8 + dd] * kc2[(8 + dd) >> 1][dd & 1];
            c0 += rel_w[(n * 7 + w) * 16 + dd]     * kc2[(16 + dd) >> 1][dd & 1];
            c1 += rel_w[(n * 7 + w) * 16 + 8 + dd] * kc2[(24 + dd) >> 1][dd & 1];
        }
        rhw[w][lane]     = a0 + a1;
        rhw[7 + w][lane] = c0 + c1;
    }
    __syncthreads();   // barrier 1: staging + rhw visible

    // ---- QK: wave w owns cells k = w + 8c; packed f32x2 dots; local max ----
    const int spc = py * 14 + px;
    float l[7];
    float lm = -1e30f;
    #pragma unroll
    for (int c = 0; c < 7; ++c) {
        const int k = w + c * NW;
        if (k < KK) {                       // wave-uniform
            int i = k / 7, j = k - i * 7;
            const unsigned short* qr = &stq[(spc + i * 14 + j) * VSTR];
            f32x2 s0 = {0.f, 0.f}, s1 = {0.f, 0.f}, s2 = {0.f, 0.f}, s3 = {0.f, 0.f};
            #pragma unroll
            for (int c4 = 0; c4 < 4; ++c4) {
                uint4 qv = *(const uint4*)&qr[c4 * 8];
                f32x2 qa = {bf2f_lo(qv.x), bf2f_hi(qv.x)};
                f32x2 qb = {bf2f_lo(qv.y), bf2f_hi(qv.y)};
                f32x2 qc = {bf2f_lo(qv.z), bf2f_hi(qv.z)};
                f32x2 qd = {bf2f_lo(qv.w), bf2f_hi(qv.w)};
                s0 = s0 + kc2[c4 * 4 + 0] * qa;
                s1 = s1 + kc2[c4 * 4 + 1] * qb;
                s2 = s2 + kc2[c4 * 4 + 2] * qc;
                s3 = s3 + kc2[c4 * 4 + 3] * qd;
            }
            f32x2 st = (s0 + s1) + (s2 + s3);
            float lv = (rhw[i][lane] + rhw[7 + j][lane]) + (st.x + st.y);
            l[c] = lv;
            lm = fmaxf(lm, lv);
        } else {
            l[c] = -1e30f;
        }
    }
    float ls = 0.f;
    float* Lme = &Llds[lane * LSTR];
    #pragma unroll
    for (int c = 0; c < 7; ++c) {
        const int k = w + c * NW;
        if (k < KK) {
            float e = __expf(l[c] - lm);
            ls += e;
            Lme[k] = e;
        }
    }
    mpart[w][lane] = lm;
    spart[w][lane] = ls;
    __syncthreads();   // barrier 2: partials + Llds visible

    // ---- merge partials: m, s, per-wave factors fw[] (inv folded in) ----
    float m = mpart[0][lane];
    #pragma unroll
    for (int ww = 1; ww < NW; ++ww) m = fmaxf(m, mpart[ww][lane]);
    float fw[NW];
    float s = 0.f;
    #pragma unroll
    for (int ww = 0; ww < NW; ++ww) {
        float f = __expf(mpart[ww][lane] - m);
        s += spart[ww][lane] * f;
        fw[ww] = f;
    }
    const float inv = 1.f / s;
    #pragma unroll
    for (int ww = 0; ww < NW; ++ww) fw[ww] *= inv;

    // ---- PV: wave w owns d = 4w..4w+3; e-values via b128 chunks ----
    const int d0 = w * 4;
    const float* Lrow = &Llds[lane * LSTR];
    f32x2 o01 = {0.f, 0.f}, o23 = {0.f, 0.f};
    #pragma unroll
    for (int jc = 0; jc < 12; ++jc) {
        f32x4 e4 = *(const f32x4*)&Lrow[jc * 4];
        #pragma unroll
        for (int q = 0; q < 4; ++q) {
            const int k = jc * 4 + q;              // 0..47, compile-time
            const int i = k / 7, j = k - i * 7;
            int sp = spc + i * 14 + j;
            float a = e4[q] * fw[k & 7];
            f32x2 a2 = {a, a};
            uint2 vv = *(const uint2*)&stv[sp * VSTR + d0];
            f32x2 v01 = {bf2f_lo(vv.x), bf2f_hi(vv.x)};
            f32x2 v23 = {bf2f_lo(vv.y), bf2f_hi(vv.y)};
            o01 = o01 + a2 * v01;
            o23 = o23 + a2 * v23;
        }
    }
    {   // tail cell k = 48
        const int k = 48, i = 6, j = 6;
        int sp = spc + i * 14 + j;
        float a = Lrow[k] * fw[k & 7];
        f32x2 a2 = {a, a};
        uint2 vv = *(const uint2*)&stv[sp * VSTR + d0];
        f32x2 v01 = {bf2f_lo(vv.x), bf2f_hi(vv.x)};
        f32x2 v23 = {bf2f_lo(vv.y), bf2f_hi(vv.y)};
        o01 = o01 + a2 * v01;
        o23 = o23 + a2 * v23;
    }
    const size_t ob = ((size_t)(b * NH + n) * HD + d0) * HW + pix;
    out[ob]          = o01.x;
    out[ob + HW]     = o01.y;
    out[ob + 2 * HW] = o23.x;
    out[ob + 3 * HW] = o23.y;
}

extern "C" void kernel_launch(void* const* d_in, const int* in_sizes, int n_in,
                              void* d_out, int out_size, void* d_ws, size_t ws_size,
                              hipStream_t stream) {
    const float* x     = (const float*)d_in[0];
    const float* Wk    = (const float*)d_in[1];
    const float* Wq    = (const float*)d_in[2];
    const float* Wv    = (const float*)d_in[3];
    const float* rel_h = (const float*)d_in[4];
    const float* rel_w = (const float*)d_in[5];

    char* wsb = (char*)d_ws;
    float*          kmap = (float*)wsb;
    unsigned short* qmap = (unsigned short*)(wsb + QOFFB);
    unsigned short* vmap = (unsigned short*)(wsb + VOFFB);
    float* out = (float*)d_out;

    hipLaunchKernelGGL(proj_kernel, dim3(98, 12), dim3(512), 0, stream,
                       x, Wk, Wq, Wv, kmap, qmap, vmap);
    hipLaunchKernelGGL(attn_kernel, dim3(784),    dim3(512), 0, stream,
                       kmap, qmap, vmap, rel_h, rel_w, out);
}